// Round 4
// baseline (28.506 us; speedup 1.0000x reference)
//
#include <hip/hip_runtime.h>

// out[b][s][d] = W[d][s] + bias[d], b<4, s<4096, d<1024
// W: [1024][8192] fp32 row-major; out: [4][4096][1024] fp32.
//
// R4 design: block = (batch, 16-row s-chunk). Each block writes ONE
// contiguous 64 KB span of out (dense write streams, fill-kernel-like),
// staging the transpose through a full-width LDS tile [16][1024] (64 KB).
// W columns are re-read per batch (4x) but the 16.8 MB active region is
// L3-resident, so HBM read traffic stays ~17 MB.
// History: NT load/store -19% (R2); occupancy 4->8 blocks/CU neutral (R3).

constexpr int S = 4096;
constexpr int D = 1024;
constexpr int MAXLEN = 8192;
constexpr int BATCH = 4;
constexpr int TS = 16;            // s-rows per block
constexpr int NTS = S / TS;       // 256 s-tiles per batch

__global__ __launch_bounds__(256)
void pos_emb_kernel(const float* __restrict__ W,
                    const float* __restrict__ bias,
                    float* __restrict__ out)
{
    __shared__ float tile[TS][D];         // 64 KB: tile[sl][d] = W[d][s0+sl]

    const int b  = blockIdx.x / NTS;      // batch (slow)
    const int ts = blockIdx.x % NTS;      // s-tile (fast: dense s in launch order)
    const int s0 = ts * TS;
    const int tid = threadIdx.x;

    // ---- Load + transpose: W[d][s0..s0+15] -> tile[sl][d] ----
    // Row d's 16 floats = 4 float4s. 4 lanes per row (c = f4 index),
    // 64 rows per pass via r0 = tid>>2 in 0..63, 16 passes covering d<1024.
    {
        const int c  = tid & 3;           // float4 index within the s-row
        const int r0 = tid >> 2;          // row base 0..63
        #pragma unroll
        for (int p = 0; p < 16; ++p) {
            const int d = r0 + p * 64;
            const float4 v = *reinterpret_cast<const float4*>(
                &W[(size_t)d * MAXLEN + s0 + c * 4]);
            tile[c * 4 + 0][d] = v.x;
            tile[c * 4 + 1][d] = v.y;
            tile[c * 4 + 2][d] = v.z;
            tile[c * 4 + 3][d] = v.w;
        }
    }
    __syncthreads();

    // ---- Store: 16 contiguous 4-KB out rows (64 KB dense span) ----
    // thread t owns float4 column c4 = t (0..255); loops the 16 rows.
    {
        const int c4 = tid;
        const float4 bv = *reinterpret_cast<const float4*>(&bias[c4 * 4]);
        float* outB = out + (size_t)b * S * D + (size_t)s0 * D;
        #pragma unroll
        for (int sl = 0; sl < TS; ++sl) {
            float4 v;
            v.x = tile[sl][c4 * 4 + 0] + bv.x;
            v.y = tile[sl][c4 * 4 + 1] + bv.y;
            v.z = tile[sl][c4 * 4 + 2] + bv.z;
            v.w = tile[sl][c4 * 4 + 3] + bv.w;
            *reinterpret_cast<float4*>(&outB[(size_t)sl * D + c4 * 4]) = v;
        }
    }
}

extern "C" void kernel_launch(void* const* d_in, const int* in_sizes, int n_in,
                              void* d_out, int out_size, void* d_ws, size_t ws_size,
                              hipStream_t stream) {
    // setup_inputs order: x (unused), W, b
    const float* W    = (const float*)d_in[1];
    const float* bias = (const float*)d_in[2];
    float* out        = (float*)d_out;

    const int grid = BATCH * NTS;         // 1024 blocks, 256 threads
    pos_emb_kernel<<<grid, 256, 0, stream>>>(W, bias, out);
}

// Round 5
// 18.597 us; speedup vs baseline: 1.5328x; 1.5328x over previous
//
#include <hip/hip_runtime.h>

// out[b][s][d] = W[d][s] + bias[d], b<4, s<4096, d<1024
// W: [1024][8192] fp32 row-major; out: [4][4096][1024] fp32.
//
// R5: isolate write-fragment size. TD=256 x TS=32 tile: W reads stay
// single-pass full-line (128 B/row), batch replication in-register,
// but each output write fragment is 1 KB (one full wave store run)
// instead of R3's 256 B -> 4x better DRAM page locality on the
// write-dominated stream.
// History: NT -19% (R2); occupancy 4<->8 blk/CU neutral (R3);
// batch-in-grid read amplification +59% (R4).

constexpr int S = 4096;
constexpr int D = 1024;
constexpr int MAXLEN = 8192;
constexpr int BATCH = 4;
constexpr int TS = 32;            // s-rows per block
constexpr int TD = 256;           // d-cols per block
constexpr int RS = TD + 12;       // LDS row stride (floats): 16B-aligned rows,
                                  // scatter writes 4-way aliased (1.58x, hidden)
constexpr int NTD = D / TD;       // 4  (fast grid index)
constexpr int NTS = S / TS;       // 128

__global__ __launch_bounds__(512)
void pos_emb_kernel(const float* __restrict__ W,
                    const float* __restrict__ bias,
                    float* __restrict__ out)
{
    __shared__ float tile[TS][RS];        // tile[sl][dl] = W[d0+dl][s0+sl]

    const int td = blockIdx.x % NTD;      // fast: co-scheduled blocks finish a dense d-slab
    const int ts = blockIdx.x / NTD;
    const int s0 = ts * TS;
    const int d0 = td * TD;
    const int tid = threadIdx.x;

    // ---- Load: W rows d0..d0+255, 128 B (full line) each; transpose-scatter ----
    // 8 float4 per 32-float row; 64 rows per pass; 4 passes.
    {
        const int c  = tid & 7;           // float4 index within the s-row
        const int r0 = tid >> 3;          // row base 0..63
        #pragma unroll
        for (int p = 0; p < 4; ++p) {
            const int dl = r0 + p * 64;
            const float4 v = *reinterpret_cast<const float4*>(
                &W[(size_t)(d0 + dl) * MAXLEN + s0 + c * 4]);
            tile[c * 4 + 0][dl] = v.x;
            tile[c * 4 + 1][dl] = v.y;
            tile[c * 4 + 2][dl] = v.z;
            tile[c * 4 + 3][dl] = v.w;
        }
    }
    __syncthreads();

    // ---- Store: 32 out-row fragments of 1 KB each, x4 batches ----
    // wave = one sl row (c4 sweeps 64 float4s = 1 KB contiguous run).
    {
        const int c4 = tid & 63;          // float4 index along d (64 per row)
        const int rs = tid >> 6;          // s-row base 0..7
        const float4 bv = *reinterpret_cast<const float4*>(&bias[d0 + c4 * 4]);
        #pragma unroll
        for (int i = 0; i < 4; ++i) {
            const int sl = rs + i * 8;
            const float4 t = *reinterpret_cast<const float4*>(&tile[sl][c4 * 4]);
            float4 v;
            v.x = t.x + bv.x;
            v.y = t.y + bv.y;
            v.z = t.z + bv.z;
            v.w = t.w + bv.w;
            const size_t base = (size_t)(s0 + sl) * D + d0 + c4 * 4;
            #pragma unroll
            for (int b = 0; b < BATCH; ++b) {
                *reinterpret_cast<float4*>(&out[base + (size_t)b * S * D]) = v;
            }
        }
    }
}

extern "C" void kernel_launch(void* const* d_in, const int* in_sizes, int n_in,
                              void* d_out, int out_size, void* d_ws, size_t ws_size,
                              hipStream_t stream) {
    // setup_inputs order: x (unused), W, b
    const float* W    = (const float*)d_in[1];
    const float* bias = (const float*)d_in[2];
    float* out        = (float*)d_out;

    const int grid = NTD * NTS;           // 512 blocks, 512 threads
    pos_emb_kernel<<<grid, 512, 0, stream>>>(W, bias, out);
}

// Round 6
// 18.432 us; speedup vs baseline: 1.5466x; 1.0090x over previous
//
#include <hip/hip_runtime.h>

// out[b][s][d] = W[d][s] + bias[d], b<4, s<4096, d<1024
// W: [1024][8192] fp32 row-major; out: [4][4096][1024] fp32.
//
// R6: double-buffered 2-tile pipeline per block (Little's-law fix).
// Each block owns (s-chunk of 32) x (two adjacent d-tiles of 64).
// ALL global loads (both tiles) are issued up front into registers;
// stores of tile 0 overlap the in-flight loads of tile 1, keeping the
// read stream outstanding through the store phase instead of bursting.
// Geometry per tile = R3 (TS=32, TD=64, +1 pad). Batch replication
// stays in-register (single-pass W read).
// History: NT -19% (R2); occupancy 4<->8 blk/CU neutral (R3);
// batch-in-grid read amp +59% (R4); 1KB write fragments neutral (R5).

constexpr int S = 4096;
constexpr int D = 1024;
constexpr int MAXLEN = 8192;
constexpr int BATCH = 4;
constexpr int TS = 32;            // s-rows per tile
constexpr int TD = 64;            // d-cols per tile
constexpr int PAD = 1;            // LDS row stride 33 -> 2 lanes/bank (free)
constexpr int NTS = S / TS;       // 128
constexpr int NTD = D / TD;       // 16
constexpr int TPB = 2;            // tiles per block (pipelined along d)

__global__ __launch_bounds__(256)
void pos_emb_kernel(const float* __restrict__ W,
                    const float* __restrict__ bias,
                    float* __restrict__ out)
{
    __shared__ float buf[2][TD][TS + PAD];   // 2 x 8.4 KB

    const int ts     = blockIdx.x % NTS;
    const int tdBase = (blockIdx.x / NTS) * TPB;
    const int s0     = ts * TS;
    const int tid    = threadIdx.x;

    // load-phase mapping: 8 float4 per 32-float s-row, 32 rows per pass
    const int lc = tid & 7;    // float4 index within s-row
    const int lr = tid >> 3;   // d-row base 0..31
    // store-phase mapping: 16 float4 along d, 16 s-rows per pass
    const int cd = tid & 15;
    const int rs = tid >> 4;

    // ---- Issue ALL global loads up front (8 float4 in flight/thread) ----
    float4 v0[2], v1[2];
    {
        const int d0a = tdBase * TD;
        const int d0b = (tdBase + 1) * TD;
        #pragma unroll
        for (int i = 0; i < 2; ++i) {
            const int dl = lr + i * 32;
            v0[i] = *reinterpret_cast<const float4*>(
                &W[(size_t)(d0a + dl) * MAXLEN + s0 + lc * 4]);
        }
        #pragma unroll
        for (int i = 0; i < 2; ++i) {
            const int dl = lr + i * 32;
            v1[i] = *reinterpret_cast<const float4*>(
                &W[(size_t)(d0b + dl) * MAXLEN + s0 + lc * 4]);
        }
    }

    // ---- buf0 <- tile0 (waits only on v0; v1 stays in flight) ----
    #pragma unroll
    for (int i = 0; i < 2; ++i) {
        const int dl = lr + i * 32;
        buf[0][dl][lc * 4 + 0] = v0[i].x;
        buf[0][dl][lc * 4 + 1] = v0[i].y;
        buf[0][dl][lc * 4 + 2] = v0[i].z;
        buf[0][dl][lc * 4 + 3] = v0[i].w;
    }
    __syncthreads();

    // ---- Store tile0 (overlaps v1 loads), then commit buf1 ----
    {
        const int d0 = tdBase * TD;
        const float4 bv = *reinterpret_cast<const float4*>(&bias[d0 + cd * 4]);
        #pragma unroll
        for (int i = 0; i < 2; ++i) {
            const int sl = rs + i * 16;
            float4 v;
            v.x = buf[0][cd * 4 + 0][sl] + bv.x;
            v.y = buf[0][cd * 4 + 1][sl] + bv.y;
            v.z = buf[0][cd * 4 + 2][sl] + bv.z;
            v.w = buf[0][cd * 4 + 3][sl] + bv.w;
            const size_t base = (size_t)(s0 + sl) * D + d0 + cd * 4;
            #pragma unroll
            for (int b = 0; b < BATCH; ++b) {
                *reinterpret_cast<float4*>(&out[base + (size_t)b * S * D]) = v;
            }
        }
    }
    #pragma unroll
    for (int i = 0; i < 2; ++i) {
        const int dl = lr + i * 32;
        buf[1][dl][lc * 4 + 0] = v1[i].x;
        buf[1][dl][lc * 4 + 1] = v1[i].y;
        buf[1][dl][lc * 4 + 2] = v1[i].z;
        buf[1][dl][lc * 4 + 3] = v1[i].w;
    }
    __syncthreads();

    // ---- Store tile1 ----
    {
        const int d0 = (tdBase + 1) * TD;
        const float4 bv = *reinterpret_cast<const float4*>(&bias[d0 + cd * 4]);
        #pragma unroll
        for (int i = 0; i < 2; ++i) {
            const int sl = rs + i * 16;
            float4 v;
            v.x = buf[1][cd * 4 + 0][sl] + bv.x;
            v.y = buf[1][cd * 4 + 1][sl] + bv.y;
            v.z = buf[1][cd * 4 + 2][sl] + bv.z;
            v.w = buf[1][cd * 4 + 3][sl] + bv.w;
            const size_t base = (size_t)(s0 + sl) * D + d0 + cd * 4;
            #pragma unroll
            for (int b = 0; b < BATCH; ++b) {
                *reinterpret_cast<float4*>(&out[base + (size_t)b * S * D]) = v;
            }
        }
    }
}

extern "C" void kernel_launch(void* const* d_in, const int* in_sizes, int n_in,
                              void* d_out, int out_size, void* d_ws, size_t ws_size,
                              hipStream_t stream) {
    // setup_inputs order: x (unused), W, b
    const float* W    = (const float*)d_in[1];
    const float* bias = (const float*)d_in[2];
    float* out        = (float*)d_out;

    const int grid = NTS * (NTD / TPB);   // 1024 blocks, 256 threads
    pos_emb_kernel<<<grid, 256, 0, stream>>>(W, bias, out);
}